// Round 1
// 335.042 us; speedup vs baseline: 1.0371x; 1.0371x over previous
//
#include <hip/hip_runtime.h>
#include <cstdint>
#include <cstddef>

#define D 128

typedef unsigned short ushort_t;
typedef unsigned int uint_t;
typedef __attribute__((ext_vector_type(8))) short bf16x8;
typedef __attribute__((ext_vector_type(4))) float f32x4;

static __device__ __forceinline__ unsigned short f2bf(float f) {
    unsigned int u = __float_as_uint(f);
    u = (u + 0x7FFFu + ((u >> 16) & 1u)) >> 16;  // RNE
    return (unsigned short)u;
}
static __device__ __forceinline__ float bf_lo(uint_t v) {
    return __uint_as_float(v << 16);
}
static __device__ __forceinline__ float bf_hi(uint_t v) {
    return __uint_as_float(v & 0xFFFF0000u);
}

// ================= CSR build: two-level counting sort =================

__global__ __launch_bounds__(256) void bkt_hist(const int* __restrict__ dst,
                                                int* __restrict__ bhist, int E) {
    __shared__ int lh[512];
    int t = threadIdx.x;
    lh[t] = 0;
    lh[t + 256] = 0;
    __syncthreads();
    int base = blockIdx.x * 4096;
#pragma unroll
    for (int i = 0; i < 16; ++i) {
        int e = base + i * 256 + t;
        if (e < E) atomicAdd(&lh[dst[e] >> 8], 1);
    }
    __syncthreads();
    if (lh[t]) atomicAdd(&bhist[t], lh[t]);
    if (lh[t + 256]) atomicAdd(&bhist[t + 256], lh[t + 256]);
}

__global__ __launch_bounds__(512) void bkt_scan(const int* __restrict__ bhist,
                                                int* __restrict__ boff,
                                                int* __restrict__ bcur,
                                                int* __restrict__ row_ptr,
                                                int N, int E) {
    __shared__ int s[512];
    int t = threadIdx.x;
    int v = bhist[t];
    s[t] = v;
    __syncthreads();
    for (int off = 1; off < 512; off <<= 1) {
        int u = (t >= off) ? s[t - off] : 0;
        __syncthreads();
        s[t] += u;
        __syncthreads();
    }
    int ex = s[t] - v;
    boff[t] = ex;
    bcur[t] = ex;
    if (t == 511) boff[512] = s[511];
    if (t == 0) row_ptr[N] = E;
}

__global__ __launch_bounds__(256) void bkt_scatter(const int* __restrict__ src,
                                                   const int* __restrict__ dst,
                                                   int* __restrict__ bcur,
                                                   int* __restrict__ ebuf, int E) {
    __shared__ int lh[512];
    __shared__ int gb[512];
    int t = threadIdx.x;
    lh[t] = 0;
    lh[t + 256] = 0;
    __syncthreads();
    int base = blockIdx.x * 4096;
    unsigned pk[16];  // rank<<17 | bkt<<8 | dlocal
#pragma unroll
    for (int i = 0; i < 16; ++i) {
        int e = base + i * 256 + t;
        unsigned p = 0xFFFFFFFFu;
        if (e < E) {
            int d = dst[e];
            int bkt = d >> 8;
            int r = atomicAdd(&lh[bkt], 1);
            p = ((unsigned)r << 17) | ((unsigned)bkt << 8) | (unsigned)(d & 255);
        }
        pk[i] = p;
    }
    __syncthreads();
    if (lh[t]) gb[t] = atomicAdd(&bcur[t], lh[t]);
    if (lh[t + 256]) gb[t + 256] = atomicAdd(&bcur[t + 256], lh[t + 256]);
    __syncthreads();
#pragma unroll
    for (int i = 0; i < 16; ++i) {
        int e = base + i * 256 + t;
        if (e < E) {
            unsigned p = pk[i];
            int bkt = (p >> 8) & 511;
            int r = (int)(p >> 17);
            ebuf[gb[bkt] + r] = src[e] | ((int)(p & 255) << 20);
        }
    }
}

__global__ __launch_bounds__(256) void bkt_build(const int* __restrict__ ebuf,
                                                 const int* __restrict__ boff,
                                                 int* __restrict__ row_ptr,
                                                 int* __restrict__ csr, int N) {
    __shared__ int lcnt[256];
    __shared__ int lofs[256];
    __shared__ int lcur[256];
    int t = threadIdx.x;
    int b = blockIdx.x;
    int base = b << 8;
    int ebeg = boff[b], eend = boff[b + 1];
    lcnt[t] = 0;
    __syncthreads();
    for (int e = ebeg + t; e < eend; e += 256)
        atomicAdd(&lcnt[((unsigned)ebuf[e]) >> 20], 1);
    __syncthreads();
    int v = lcnt[t];
    lofs[t] = v;
    __syncthreads();
    for (int off = 1; off < 256; off <<= 1) {
        int u = (t >= off) ? lofs[t - off] : 0;
        __syncthreads();
        lofs[t] += u;
        __syncthreads();
    }
    int ex = lofs[t] - v;
    __syncthreads();
    lofs[t] = ex;
    lcur[t] = 0;
    if (base + t < N) row_ptr[base + t] = ebeg + ex;
    __syncthreads();
    for (int e = ebeg + t; e < eend; e += 256) {
        int u = ebuf[e];
        int d = ((unsigned)u) >> 20;
        int r = atomicAdd(&lcur[d], 1);
        csr[ebeg + lofs[d] + r] = u & 0xFFFFF;
    }
}

// ================= fp32 -> bf16 casts =================

__global__ __launch_bounds__(256) void cast_x_kernel(const float* __restrict__ src,
                                                     ushort_t* __restrict__ dst,
                                                     long n) {
    long i = ((long)blockIdx.x * 256 + threadIdx.x) * 8;
    if (i >= n) return;
    float4 a = *(const float4*)(src + i);
    float4 b = *(const float4*)(src + i + 4);
    uint4 o;
    o.x = (uint_t)f2bf(a.x) | ((uint_t)f2bf(a.y) << 16);
    o.y = (uint_t)f2bf(a.z) | ((uint_t)f2bf(a.w) << 16);
    o.z = (uint_t)f2bf(b.x) | ((uint_t)f2bf(b.y) << 16);
    o.w = (uint_t)f2bf(b.z) | ((uint_t)f2bf(b.w) << 16);
    *(uint4*)(dst + i) = o;
}

__global__ __launch_bounds__(256) void cast_w_kernel(const float* __restrict__ s0,
                                                     const float* __restrict__ s1,
                                                     const float* __restrict__ s2,
                                                     const float* __restrict__ s3,
                                                     ushort_t* __restrict__ d0,
                                                     ushort_t* __restrict__ d1,
                                                     ushort_t* __restrict__ d2,
                                                     ushort_t* __restrict__ d3) {
    const float* s = (blockIdx.y == 0) ? s0 : (blockIdx.y == 1) ? s1
                   : (blockIdx.y == 2) ? s2 : s3;
    ushort_t* d = (blockIdx.y == 0) ? d0 : (blockIdx.y == 1) ? d1
                : (blockIdx.y == 2) ? d2 : d3;
    long i = ((long)blockIdx.x * 256 + threadIdx.x) * 8;
    float4 a = *(const float4*)(s + i);
    float4 b = *(const float4*)(s + i + 4);
    uint4 o;
    o.x = (uint_t)f2bf(a.x) | ((uint_t)f2bf(a.y) << 16);
    o.y = (uint_t)f2bf(a.z) | ((uint_t)f2bf(a.w) << 16);
    o.z = (uint_t)f2bf(b.x) | ((uint_t)f2bf(b.y) << 16);
    o.w = (uint_t)f2bf(b.z) | ((uint_t)f2bf(b.w) << 16);
    *(uint4*)(d + i) = o;
}

// ================= mean aggregation over bf16 rows =================
// One wave per node. All <=64 neighbor indices preloaded by ONE coalesced csr
// load and distributed via __shfl (removes per-chunk serial csr-latency leg).
// Gathers are uint4 (16B/lane, 16 lanes/row, 4 rows per wave instruction);
// 16-edge chunks put 4KB/wave in flight per memory leg.

static __device__ __forceinline__ void acc8(uint4 v, float a[8]) {
    a[0] += bf_lo(v.x); a[1] += bf_hi(v.x);
    a[2] += bf_lo(v.y); a[3] += bf_hi(v.y);
    a[4] += bf_lo(v.z); a[5] += bf_hi(v.z);
    a[6] += bf_lo(v.w); a[7] += bf_hi(v.w);
}

static __device__ __forceinline__ uint4 grow(const ushort_t* __restrict__ xin,
                                             int s, int l16) {
    unsigned off = ((unsigned)s << 8) | ((unsigned)l16 << 4);  // bytes
    return *(const uint4*)((const char*)xin + off);
}

__global__ __launch_bounds__(256) void agg_b_kernel(const ushort_t* __restrict__ xin,
                                                    const int* __restrict__ csr,
                                                    const int* __restrict__ row_ptr,
                                                    ushort_t* __restrict__ aggb, int N) {
    int node = blockIdx.x * 4 + (threadIdx.x >> 6);
    if (node >= N) return;
    int lane = threadIdx.x & 63;
    int g = lane >> 4;    // row group 0..3
    int l16 = lane & 15;  // 16B segment within a 256B row
    int beg = row_ptr[node], end = row_ptr[node + 1];
    int deg = end - beg;
    float a[8] = {0.f, 0.f, 0.f, 0.f, 0.f, 0.f, 0.f, 0.f};

    if (deg > 0) {
        int deg64 = min(deg, 64);
        int myidx = csr[beg + min(lane, deg - 1)];  // one coalesced index load
        int e = 0;
        for (; e + 16 <= deg64; e += 16) {
            int s0 = __shfl(myidx, e + g);
            int s1 = __shfl(myidx, e + 4 + g);
            int s2 = __shfl(myidx, e + 8 + g);
            int s3 = __shfl(myidx, e + 12 + g);
            uint4 v0 = grow(xin, s0, l16);
            uint4 v1 = grow(xin, s1, l16);
            uint4 v2 = grow(xin, s2, l16);
            uint4 v3 = grow(xin, s3, l16);
            acc8(v0, a); acc8(v1, a); acc8(v2, a); acc8(v3, a);
        }
        if (e + 8 <= deg64) {
            int s0 = __shfl(myidx, e + g);
            int s1 = __shfl(myidx, e + 4 + g);
            uint4 v0 = grow(xin, s0, l16);
            uint4 v1 = grow(xin, s1, l16);
            acc8(v0, a); acc8(v1, a);
            e += 8;
        }
        for (; e < deg64; e += 4) {  // masked tail, <=7 edges
            int ee = min(e + g, deg64 - 1);
            int s = __shfl(myidx, ee);
            uint4 v = grow(xin, s, l16);
            if (e + g < deg64) acc8(v, a);
        }
        for (int e2 = 64; e2 < deg; e2 += 4) {  // rare deg>64 fallback
            int s = csr[beg + min(e2 + g, deg - 1)];
            uint4 v = grow(xin, s, l16);
            if (e2 + g < deg) acc8(v, a);
        }
    }

#pragma unroll
    for (int i = 0; i < 8; ++i) {
        a[i] += __shfl_xor(a[i], 16);
        a[i] += __shfl_xor(a[i], 32);
    }
    if (g == 0) {
        float inv = 1.0f / fmaxf((float)deg, 1.0f);
        uint4 o;
        o.x = (uint_t)f2bf(a[0] * inv) | ((uint_t)f2bf(a[1] * inv) << 16);
        o.y = (uint_t)f2bf(a[2] * inv) | ((uint_t)f2bf(a[3] * inv) << 16);
        o.z = (uint_t)f2bf(a[4] * inv) | ((uint_t)f2bf(a[5] * inv) << 16);
        o.w = (uint_t)f2bf(a[6] * inv) | ((uint_t)f2bf(a[7] * inv) << 16);
        unsigned off = ((unsigned)node << 8) | ((unsigned)l16 << 4);
        *(uint4*)((char*)aggb + off) = o;
    }
}

// ================= MFMA GEMM (LDS-staged): out = [aggb|xinb] @ [Wl|Wr]^T + bias ====
// Block: 256 thr = 4 waves; tile 128 nodes x 128 cols. Wave (wm,wc) owns 64x64.
// Per K-chunk of 32: stage sA(8KB)+sW(8KB) with fully-coalesced global loads,
// fragments via ds_read_b128 (k-contiguous rows), 16 MFMA/wave/chunk.
// A-frag: lane=row m (l15), k=quad*8+j.  B-frag: lane=col j, same k slice.
// C/D: col=lane&15, row=quad*4+reg.

__global__ __launch_bounds__(256) void gemm_mfma(const ushort_t* __restrict__ Aagg,
                                                 const ushort_t* __restrict__ Ax,
                                                 const ushort_t* __restrict__ Wl,
                                                 const ushort_t* __restrict__ Wr,
                                                 const float* __restrict__ bias,
                                                 ushort_t* __restrict__ out_bf,
                                                 float* __restrict__ out_f32,
                                                 int N, int relu_bf) {
    __shared__ ushort_t sA[128 * 32];  // 8 KB, row-major, row stride 32 elems
    __shared__ ushort_t sW[128 * 32];  // 8 KB
    int tid = threadIdx.x;
    int wave = tid >> 6, lane = tid & 63;
    int quad = lane >> 4, l15 = lane & 15;
    int wm = wave & 1, wc = wave >> 1;
    int n0 = blockIdx.x * 128;

    // staging coords: each thread moves 2x16B for A and 2x16B for W per chunk
    int sr = tid >> 2;          // rows 0..63 (iter adds 64)
    int sseg = (tid & 3) * 8;   // elem offset within 32-elem row

    f32x4 acc[4][4];
#pragma unroll
    for (int mt = 0; mt < 4; ++mt)
#pragma unroll
        for (int nt = 0; nt < 4; ++nt) acc[mt][nt] = (f32x4){0.f, 0.f, 0.f, 0.f};

    int ga0 = min(n0 + sr, N - 1);
    int ga1 = min(n0 + sr + 64, N - 1);

#pragma unroll
    for (int c = 0; c < 8; ++c) {
        const ushort_t* Ab = (c < 4) ? Aagg : Ax;
        const ushort_t* Wb = (c < 4) ? Wl : Wr;
        int koff = (c & 3) * 32 + sseg;
        bf16x8 va0 = *(const bf16x8*)(Ab + (size_t)ga0 * D + koff);
        bf16x8 va1 = *(const bf16x8*)(Ab + (size_t)ga1 * D + koff);
        bf16x8 vw0 = *(const bf16x8*)(Wb + (size_t)sr * D + koff);
        bf16x8 vw1 = *(const bf16x8*)(Wb + (size_t)(sr + 64) * D + koff);
        __syncthreads();  // previous chunk fully consumed
        *(bf16x8*)&sA[sr * 32 + sseg] = va0;
        *(bf16x8*)&sA[(sr + 64) * 32 + sseg] = va1;
        *(bf16x8*)&sW[sr * 32 + sseg] = vw0;
        *(bf16x8*)&sW[(sr + 64) * 32 + sseg] = vw1;
        __syncthreads();

        bf16x8 af[4], wf[4];
#pragma unroll
        for (int mt = 0; mt < 4; ++mt)
            af[mt] = *(const bf16x8*)&sA[(wm * 64 + mt * 16 + l15) * 32 + quad * 8];
#pragma unroll
        for (int nt = 0; nt < 4; ++nt)
            wf[nt] = *(const bf16x8*)&sW[(wc * 64 + nt * 16 + l15) * 32 + quad * 8];
#pragma unroll
        for (int mt = 0; mt < 4; ++mt)
#pragma unroll
            for (int nt = 0; nt < 4; ++nt)
                acc[mt][nt] = __builtin_amdgcn_mfma_f32_16x16x32_bf16(
                    af[mt], wf[nt], acc[mt][nt], 0, 0, 0);
    }

#pragma unroll
    for (int mt = 0; mt < 4; ++mt) {
#pragma unroll
        for (int nt = 0; nt < 4; ++nt) {
            int col = wc * 64 + nt * 16 + l15;
            float bv = bias[col];
#pragma unroll
            for (int reg = 0; reg < 4; ++reg) {
                int row = n0 + wm * 64 + mt * 16 + quad * 4 + reg;
                if (row < N) {
                    float v = acc[mt][nt][reg] + bv;
                    if (relu_bf) {
                        v = fmaxf(v, 0.f);
                        out_bf[(size_t)row * D + col] = f2bf(v);
                    } else {
                        out_f32[(size_t)row * D + col] = v;
                    }
                }
            }
        }
    }
}

// ================= launch =================

extern "C" void kernel_launch(void* const* d_in, const int* in_sizes, int n_in,
                              void* d_out, int out_size, void* d_ws, size_t ws_size,
                              hipStream_t stream) {
    const float* x   = (const float*)d_in[0];
    const int*   ei  = (const int*)d_in[1];
    const float* W1l = (const float*)d_in[2];
    const float* b1  = (const float*)d_in[3];
    const float* W1r = (const float*)d_in[4];
    const float* W2l = (const float*)d_in[5];
    const float* b2  = (const float*)d_in[6];
    const float* W2r = (const float*)d_in[7];
    float* out = (float*)d_out;

    int N = in_sizes[0] / D;
    int E = in_sizes[1] / 2;
    const int* src = ei;
    const int* dst = ei + E;

    char* ws = (char*)d_ws;
    size_t off = 0;
    auto take = [&](size_t bytes) -> char* {
        char* p = ws + off;
        off += (bytes + 255) & ~(size_t)255;
        return p;
    };
    int*      row_ptr = (int*)take((size_t)(N + 1) * sizeof(int));
    int*      bhist   = (int*)take((size_t)(512 + 512 + 513) * sizeof(int));
    int*      bcur    = bhist + 512;
    int*      boff    = bhist + 1024;
    int*      ebuf    = (int*)take((size_t)E * sizeof(int));
    int*      csr     = (int*)take((size_t)E * sizeof(int));
    ushort_t* xb      = (ushort_t*)take((size_t)N * D * sizeof(ushort_t));
    ushort_t* hb      = (ushort_t*)take((size_t)N * D * sizeof(ushort_t));
    ushort_t* aggb    = (ushort_t*)take((size_t)N * D * sizeof(ushort_t));
    ushort_t* W1lb    = (ushort_t*)take((size_t)D * D * sizeof(ushort_t));
    ushort_t* W1rb    = (ushort_t*)take((size_t)D * D * sizeof(ushort_t));
    ushort_t* W2lb    = (ushort_t*)take((size_t)D * D * sizeof(ushort_t));
    ushort_t* W2rb    = (ushort_t*)take((size_t)D * D * sizeof(ushort_t));
    (void)ws_size;
    (void)n_in;
    (void)out_size;

    hipMemsetAsync(bhist, 0, 1024 * sizeof(int), stream);

    int NB = (N + 255) / 256;
    int EB = (E + 4095) / 4096;

    bkt_hist<<<EB, 256, 0, stream>>>(dst, bhist, E);
    bkt_scan<<<1, 512, 0, stream>>>(bhist, boff, bcur, row_ptr, N, E);
    bkt_scatter<<<EB, 256, 0, stream>>>(src, dst, bcur, ebuf, E);
    bkt_build<<<NB, 256, 0, stream>>>(ebuf, boff, row_ptr, csr, N);

    long nx = (long)N * D;
    cast_x_kernel<<<(int)((nx / 8 + 255) / 256), 256, 0, stream>>>(x, xb, nx);
    cast_w_kernel<<<dim3(8, 4), 256, 0, stream>>>(W1l, W1r, W2l, W2r,
                                                  W1lb, W1rb, W2lb, W2rb);

    int ablocks = (N + 3) / 4;
    int gblocks = (N + 127) / 128;

    agg_b_kernel<<<ablocks, 256, 0, stream>>>(xb, csr, row_ptr, aggb, N);
    gemm_mfma<<<gblocks, 256, 0, stream>>>(aggb, xb, W1lb, W1rb, b1, hb, nullptr, N, 1);

    agg_b_kernel<<<ablocks, 256, 0, stream>>>(hb, csr, row_ptr, aggb, N);
    gemm_mfma<<<gblocks, 256, 0, stream>>>(aggb, hb, W2lb, W2rb, b2, nullptr, out, N, 0);
}